// Round 7
// baseline (236.225 us; speedup 1.0000x reference)
//
#include <hip/hip_runtime.h>

// Batched Kalman step: G groups, S=16, M=8, fp32. One wave per group,
// 4 waves/block, wave-private LDS (no __syncthreads; same-wave DS is in-order).
//
// R7: the DS pipe was ~100% saturated in R6 (58 b128-class ops/group ~= the
// measured 794 cy/group). Rebalance onto idle pipes:
//  - cov rows read from GLOBAL (L1-hot bcast dwordx4) in step 1 -> cov never
//    staged in LDS (-9 DS ops)
//  - T3 never touches LDS: quad holds T3 row r; gather via v_mov_dpp
//    quad-rotations (VALU) and read step-8's F rows from GLOBAL (-17 DS ops)
//  - CT^T stored at step 1 (2 b32 writes) so step 5 reads 2 b128, not 8 b32
//  - keep: 2x2-blocked in-register GJ, rcp+readlane pivots, shfl-xor nm
//    reduce, v_pk_fma_f32 dots, coalesced pred_cov store via symmetry

typedef float v2f __attribute__((ext_vector_type(2)));

#define WSYNC() asm volatile("" ::: "memory")

__device__ __forceinline__ float lane_bcast(float v, int srclane) {
    return __int_as_float(__builtin_amdgcn_readlane(__float_as_int(v), srclane));
}
// quad_perm rotate-by-K within each 4-lane group (VALU pipe, no DS)
template<int CTRL>
__device__ __forceinline__ float qrot(float v) {
    return __int_as_float(__builtin_amdgcn_mov_dpp(__float_as_int(v), CTRL, 0xF, 0xF, true));
}
__device__ __forceinline__ v2f lo2(float4 v) { v2f r; r.x = v.x; r.y = v.y; return r; }
__device__ __forceinline__ v2f hi2(float4 v) { v2f r; r.x = v.z; r.y = v.w; return r; }

__global__ __launch_bounds__(256) void kalman_kernel(
    const float* __restrict__ g_in,
    const float* __restrict__ g_mean,
    const float* __restrict__ g_cov,
    const float* __restrict__ g_H,
    const float* __restrict__ g_R,
    const float* __restrict__ g_F,
    const float* __restrict__ g_Q,
    float* __restrict__ g_out,
    int G)
{
    // per-wave LDS (floats), 848 total = 3392 B:
    //  sCT [8][20] @0    sX[8][20]@160   sCTT[16][12]@320
    //  sNM [16]    @512  sNC[16][20]@528
    __shared__ __align__(16) float smem[4][848];
    const int wv   = threadIdx.x >> 6;
    const int lane = threadIdx.x & 63;
    const int g    = (blockIdx.x << 2) | wv;
    float* const sm   = smem[wv];
    float* const sCT  = sm;
    float* const sX   = sm + 160;
    float* const sCTT = sm + 320;
    float* const sNM  = sm + 512;
    float* const sNC  = sm + 528;

    const int r  = lane >> 2;        // 0..15
    const int c0 = (lane & 3) << 2;  // 0,4,8,12
    const int gi = lane >> 3;        // 0..7
    const int gj = lane & 7;         // 0..7

    const float* const Gcov = g_cov + (size_t)g * 256;
    const float* const GF   = g_F   + (size_t)g * 256;

    // ---- hoisted loads: cov quad (coalesced), H row gi (bcast), R, in ----
    const float4 cv = *reinterpret_cast<const float4*>(Gcov + lane*4);
    float4 hq[4];
    #pragma unroll
    for (int q = 0; q < 4; ++q)
        hq[q] = *reinterpret_cast<const float4*>(g_H + (size_t)g*128 + gi*16 + 4*q);
    float a   = g_R[(size_t)g*64 + gi*8 + gj];          // Ssys accumulator
    float rin = g_in[(size_t)g*8 + gi];                  // residual accumulator

    // resid = in - H@mean
    {
        v2f acc; acc.x = 0.f; acc.y = 0.f;
        #pragma unroll
        for (int q = 0; q < 4; ++q) {
            const float4 m4 = *reinterpret_cast<const float4*>(g_mean + (size_t)g*16 + 4*q);
            acc += lo2(hq[q]) * lo2(m4);
            acc += hi2(hq[q]) * hi2(m4);
        }
        rin -= acc.x + acc.y;
    }

    // ---- 1: CT = H@cov (cov sym), cov rows from GLOBAL (L1-hot bcast) ----
    float b0, b1;
    {
        v2f a0; a0.x = 0.f; a0.y = 0.f;
        v2f a1; a1.x = 0.f; a1.y = 0.f;
        #pragma unroll
        for (int q = 0; q < 4; ++q) {
            const float4 ca = *reinterpret_cast<const float4*>(Gcov + gj*16 + 4*q);
            const float4 cb = *reinterpret_cast<const float4*>(Gcov + (gj+8)*16 + 4*q);
            a0 += lo2(hq[q]) * lo2(ca);
            a0 += hi2(hq[q]) * hi2(ca);
            a1 += lo2(hq[q]) * lo2(cb);
            a1 += hi2(hq[q]) * hi2(cb);
        }
        b0 = a0.x + a0.y;
        b1 = a1.x + a1.y;
    }
    sCT[gi*20 + gj]       = b0;   // row-major for step 2
    sCT[gi*20 + gj + 8]   = b1;
    sCTT[gj*12 + gi]      = b0;   // transposed for step 5
    sCTT[(gj+8)*12 + gi]  = b1;
    WSYNC();

    // ---- 2: a = Ssys[gi][gj] = R + dot(H_gi, CT_gj) ----
    {
        v2f acc; acc.x = 0.f; acc.y = 0.f;
        #pragma unroll
        for (int q = 0; q < 4; ++q) {
            const float4 ct = *reinterpret_cast<const float4*>(sCT + gj*20 + 4*q);
            acc += lo2(hq[q]) * lo2(ct);
            acc += hi2(hq[q]) * hi2(ct);
        }
        a += acc.x + acc.y;
    }

    // ---- F row r -> regs (issued before the GJ chain to hide latency) ----
    float4 fq[4];
    #pragma unroll
    for (int q = 0; q < 4; ++q)
        fq[q] = *reinterpret_cast<const float4*>(GF + r*16 + 4*q);

    // ---- 3: 2x2-blocked Gauss-Jordan: [Ssys | CT] -> X = Ssys^-1 CT ----
    #pragma unroll
    for (int k = 0; k < 8; k += 2) {
        const int rk = k << 3, rk1 = (k+1) << 3;
        const float rka   = __shfl(a,  rk  | gj);
        const float rk1a  = __shfl(a,  rk1 | gj);
        const float rkb0  = __shfl(b0, rk  | gj);
        const float rk1b0 = __shfl(b0, rk1 | gj);
        const float rkb1  = __shfl(b1, rk  | gj);
        const float rk1b1 = __shfl(b1, rk1 | gj);
        const float ai0   = __shfl(a, (gi << 3) | k);
        const float ai1   = __shfl(a, (gi << 3) | (k+1));
        const float p00 = lane_bcast(a, rk  | k);
        const float p01 = lane_bcast(a, rk  | (k+1));
        const float p10 = lane_bcast(a, rk1 | k);
        const float p11 = lane_bcast(a, rk1 | (k+1));
        const float det  = p00*p11 - p01*p10;
        const float rdet = __builtin_amdgcn_rcpf(det);
        const float i00 =  p11*rdet, i01 = -p01*rdet;
        const float i10 = -p10*rdet, i11 =  p00*rdet;
        const float c0_ = ai0*i00 + ai1*i10;
        const float c1_ = ai0*i01 + ai1*i11;
        float na, nb0, nb1;
        if (gi == k) {
            na  = i00*rka  + i01*rk1a;
            nb0 = i00*rkb0 + i01*rk1b0;
            nb1 = i00*rkb1 + i01*rk1b1;
        } else if (gi == k+1) {
            na  = i10*rka  + i11*rk1a;
            nb0 = i10*rkb0 + i11*rk1b0;
            nb1 = i10*rkb1 + i11*rk1b1;
        } else {
            na  = a  - (c0_*rka  + c1_*rk1a);
            nb0 = b0 - (c0_*rkb0 + c1_*rk1b0);
            nb1 = b1 - (c0_*rkb1 + c1_*rk1b1);
        }
        a = na; b0 = nb0; b1 = nb1;
    }
    sX[gi*20 + gj]     = b0;
    sX[gi*20 + gj + 8] = b1;

    // ---- 4: new_mean[s] = mean[s] + sum_m X[m][s]*resid[m] (shfl-xor) ----
    {
        float p0 = b0 * rin, p1 = b1 * rin;
        p0 += __shfl_xor(p0, 8);  p1 += __shfl_xor(p1, 8);
        p0 += __shfl_xor(p0, 16); p1 += __shfl_xor(p1, 16);
        p0 += __shfl_xor(p0, 32); p1 += __shfl_xor(p1, 32);
        if (gi == 0) {
            sNM[gj]     = g_mean[(size_t)g*16 + gj]     + p0;
            sNM[gj + 8] = g_mean[(size_t)g*16 + gj + 8] + p1;
        }
    }
    WSYNC();

    // ---- 5: NC[r][c0..3] = cv - sum_m CTT[r][m] * X[m][c0..3] ----
    {
        const float4 cta = *reinterpret_cast<const float4*>(sCTT + r*12);
        const float4 ctb = *reinterpret_cast<const float4*>(sCTT + r*12 + 4);
        const float ctt[8] = {cta.x,cta.y,cta.z,cta.w, ctb.x,ctb.y,ctb.z,ctb.w};
        v2f nlo = lo2(cv), nhi = hi2(cv);
        #pragma unroll
        for (int m = 0; m < 8; ++m) {
            const float4 xq = *reinterpret_cast<const float4*>(sX + m*20 + c0);
            v2f ctv; ctv.x = ctt[m]; ctv.y = ctt[m];
            nlo -= ctv * lo2(xq);
            nhi -= ctv * hi2(xq);
        }
        float4 n; n.x = nlo.x; n.y = nlo.y; n.z = nhi.x; n.w = nhi.y;
        *reinterpret_cast<float4*>(sNC + r*20 + c0) = n;
    }
    WSYNC();

    // ---- 6: pred_mean[r] = dot(F_r, nm)  (masked coalesced store) ----
    {
        v2f acc; acc.x = 0.f; acc.y = 0.f;
        #pragma unroll
        for (int q = 0; q < 4; ++q) {
            const float4 nm = *reinterpret_cast<const float4*>(sNM + 4*q);
            acc += lo2(fq[q]) * lo2(nm);
            acc += hi2(fq[q]) * hi2(nm);
        }
        if ((lane & 3) == 0) g_out[(size_t)g*16 + r] = acc.x + acc.y;
    }

    // Q quad issued here (coalesced), consumed in step 8
    const float4 qv = *reinterpret_cast<const float4*>(g_Q + (size_t)g*256 + lane*4);

    // ---- 7: t[x] = T3[r][c0+x] = dot(F_r, NC_{c0+x})  (NC sym; 16 b128) ----
    float t0, t1, t2, t3;
    {
        float t[4];
        #pragma unroll
        for (int x = 0; x < 4; ++x) {
            v2f acc; acc.x = 0.f; acc.y = 0.f;
            #pragma unroll
            for (int q = 0; q < 4; ++q) {
                const float4 nc = *reinterpret_cast<const float4*>(sNC + (c0+x)*20 + 4*q);
                acc += lo2(fq[q]) * lo2(nc);
                acc += hi2(fq[q]) * hi2(nc);
            }
            t[x] = acc.x + acc.y;
        }
        t0 = t[0]; t1 = t[1]; t2 = t[2]; t3 = t[3];
    }

    // ---- 8: pred_cov[r][c0+x] (= [c0+x][r] by symmetry) = Q + T3_r . F_{c0+x}
    //   quad (lanes 4r..4r+3) collectively holds T3 row r; gather via DPP
    //   quad-rotations (VALU); F rows read from GLOBAL (L1-hot). Zero DS. ----
    {
        float o0 = qv.x, o1 = qv.y, o2 = qv.z, o3 = qv.w;
        // k = 0: own quad of T3 row r, F columns c0..c0+3
        {
            const int fb = c0;
            const float4 f0 = *reinterpret_cast<const float4*>(GF + (c0+0)*16 + fb);
            const float4 f1 = *reinterpret_cast<const float4*>(GF + (c0+1)*16 + fb);
            const float4 f2 = *reinterpret_cast<const float4*>(GF + (c0+2)*16 + fb);
            const float4 f3 = *reinterpret_cast<const float4*>(GF + (c0+3)*16 + fb);
            o0 += t0*f0.x + t1*f0.y + t2*f0.z + t3*f0.w;
            o1 += t0*f1.x + t1*f1.y + t2*f1.z + t3*f1.w;
            o2 += t0*f2.x + t1*f2.y + t2*f2.z + t3*f2.w;
            o3 += t0*f3.x + t1*f3.y + t2*f3.z + t3*f3.w;
        }
        // k = 1..3: rotated quads; quad_perm ctrls: rot1=0x39, rot2=0x4E, rot3=0x93
        #define STEP8_K(K, CTRL)                                                         \
        {                                                                                \
            const float u0 = qrot<CTRL>(t0), u1 = qrot<CTRL>(t1);                        \
            const float u2 = qrot<CTRL>(t2), u3 = qrot<CTRL>(t3);                        \
            const int fb = (c0 + 4*(K)) & 12;                                            \
            const float4 f0 = *reinterpret_cast<const float4*>(GF + (c0+0)*16 + fb);     \
            const float4 f1 = *reinterpret_cast<const float4*>(GF + (c0+1)*16 + fb);     \
            const float4 f2 = *reinterpret_cast<const float4*>(GF + (c0+2)*16 + fb);     \
            const float4 f3 = *reinterpret_cast<const float4*>(GF + (c0+3)*16 + fb);     \
            o0 += u0*f0.x + u1*f0.y + u2*f0.z + u3*f0.w;                                 \
            o1 += u0*f1.x + u1*f1.y + u2*f1.z + u3*f1.w;                                 \
            o2 += u0*f2.x + u1*f2.y + u2*f2.z + u3*f2.w;                                 \
            o3 += u0*f3.x + u1*f3.y + u2*f3.z + u3*f3.w;                                 \
        }
        STEP8_K(1, 0x39)
        STEP8_K(2, 0x4E)
        STEP8_K(3, 0x93)
        #undef STEP8_K
        *reinterpret_cast<float4*>(g_out + (size_t)G*16 + (size_t)g*256 + lane*4) =
            make_float4(o0, o1, o2, o3);
    }
}

extern "C" void kernel_launch(void* const* d_in, const int* in_sizes, int n_in,
                              void* d_out, int out_size, void* d_ws, size_t ws_size,
                              hipStream_t stream) {
    const float* g_in   = (const float*)d_in[0];
    const float* g_mean = (const float*)d_in[1];
    const float* g_cov  = (const float*)d_in[2];
    const float* g_H    = (const float*)d_in[3];
    const float* g_R    = (const float*)d_in[4];
    const float* g_F    = (const float*)d_in[5];
    const float* g_Q    = (const float*)d_in[6];
    float* out = (float*)d_out;
    const int G = in_sizes[2] / 256;   // cov is [G,16,16]
    kalman_kernel<<<G/4, 256, 0, stream>>>(g_in, g_mean, g_cov, g_H, g_R, g_F, g_Q, out, G);
}

// Round 8
// 173.215 us; speedup vs baseline: 1.3638x; 1.3638x over previous
//
#include <hip/hip_runtime.h>

// Batched Kalman step: G groups, S=16, M=8, fp32.
// R8: ONE GROUP PER 4-LANE QUAD. Zero LDS, zero barriers, zero DS-pipe use.
// All matrices register-resident, column-slab distributed (lane l owns cols
// 4l..4l+3 of 16-col matrices, cols {2l,2l+1} of 8-col matrices). Cross-lane
// GEMM operands via v_mov_dpp quad_perm broadcast (VALU pipe). The 8x8 SPD
// solve is an in-register Gauss-Jordan with compile-time pivot rows (no
// divergence). Loads/stores: P/R/mean/inp/Q/outputs fully coalesced float4;
// H^T and F^T are per-lane-contiguous transposed loads.

__device__ __forceinline__ float bq(float x, int t) {
    // broadcast lane t of each quad (DPP quad_perm, ctrl = t*0x55)
    switch (t & 3) {
    case 0:  return __int_as_float(__builtin_amdgcn_mov_dpp(__float_as_int(x), 0x00, 0xF, 0xF, true));
    case 1:  return __int_as_float(__builtin_amdgcn_mov_dpp(__float_as_int(x), 0x55, 0xF, 0xF, true));
    case 2:  return __int_as_float(__builtin_amdgcn_mov_dpp(__float_as_int(x), 0xAA, 0xF, 0xF, true));
    default: return __int_as_float(__builtin_amdgcn_mov_dpp(__float_as_int(x), 0xFF, 0xF, 0xF, true));
    }
}

__global__ __launch_bounds__(256) void kalman_kernel(
    const float* __restrict__ g_in,
    const float* __restrict__ g_mean,
    const float* __restrict__ g_cov,
    const float* __restrict__ g_H,
    const float* __restrict__ g_R,
    const float* __restrict__ g_F,
    const float* __restrict__ g_Q,
    float* __restrict__ g_out,
    int G)
{
    const int l = threadIdx.x & 3;                      // lane in quad
    const int g = (blockIdx.x << 6) | (threadIdx.x >> 2);  // group id

    const float* const Pp = g_cov + (size_t)g * 256;
    const float* const Hp = g_H   + (size_t)g * 128;
    const float* const Rp = g_R   + (size_t)g * 64;
    const float* const Fp = g_F   + (size_t)g * 256;
    const float* const Qp = g_Q   + (size_t)g * 256;

    // ---- batch loads (coalesced float4 / float2) ----
    float P[16][4];                       // P[k][u] = cov[k][4l+u]
    #pragma unroll
    for (int k = 0; k < 16; ++k) {
        const float4 t = *reinterpret_cast<const float4*>(Pp + k*16 + 4*l);
        P[k][0]=t.x; P[k][1]=t.y; P[k][2]=t.z; P[k][3]=t.w;
    }
    float HT[16][2];                      // HT[k][v] = H[2l+v][k] (per-lane contiguous)
    #pragma unroll
    for (int v = 0; v < 2; ++v)
    #pragma unroll
    for (int p = 0; p < 4; ++p) {
        const float4 t = *reinterpret_cast<const float4*>(Hp + (2*l+v)*16 + 4*p);
        HT[4*p+0][v]=t.x; HT[4*p+1][v]=t.y; HT[4*p+2][v]=t.z; HT[4*p+3][v]=t.w;
    }
    float S[8][2];                        // S[i][v] init R[i][2l+v]
    #pragma unroll
    for (int i = 0; i < 8; ++i) {
        const float2 t = *reinterpret_cast<const float2*>(Rp + i*8 + 2*l);
        S[i][0]=t.x; S[i][1]=t.y;
    }
    float mn[4];
    { const float4 t = *reinterpret_cast<const float4*>(g_mean + (size_t)g*16 + 4*l);
      mn[0]=t.x; mn[1]=t.y; mn[2]=t.z; mn[3]=t.w; }
    float ip[2];
    { const float2 t = *reinterpret_cast<const float2*>(g_in + (size_t)g*8 + 2*l);
      ip[0]=t.x; ip[1]=t.y; }

    // ---- CT = H @ P  (8x16, col-slab; H[i][k] = bq(HT[k][i&1], i>>1)) ----
    float CT[8][4];
    #pragma unroll
    for (int i = 0; i < 8; ++i) {
        float a0=0.f, a1=0.f, a2=0.f, a3=0.f;
        #pragma unroll
        for (int k = 0; k < 16; ++k) {
            const float h = bq(HT[k][i&1], i>>1);
            a0 += h*P[k][0]; a1 += h*P[k][1]; a2 += h*P[k][2]; a3 += h*P[k][3];
        }
        CT[i][0]=a0; CT[i][1]=a1; CT[i][2]=a2; CT[i][3]=a3;
    }

    // ---- S = CT @ H^T + R  (8x8, col-pair; CT[i][k] = bq(CT[i][k&3], k>>2)) ----
    #pragma unroll
    for (int i = 0; i < 8; ++i) {
        float a0=S[i][0], a1=S[i][1];
        #pragma unroll
        for (int k = 0; k < 16; ++k) {
            const float c = bq(CT[i][k&3], k>>2);
            a0 += c*HT[k][0]; a1 += c*HT[k][1];
        }
        S[i][0]=a0; S[i][1]=a1;
    }

    // ---- res = inp - H @ mean  (rows 2l,2l+1 per lane) ----
    float resd[2];
    {
        float a0 = ip[0], a1 = ip[1];
        #pragma unroll
        for (int k = 0; k < 16; ++k) {
            const float m = bq(mn[k&3], k>>2);
            a0 -= HT[k][0]*m; a1 -= HT[k][1]*m;
        }
        resd[0]=a0; resd[1]=a1;
    }

    // ---- Gauss-Jordan [S | I] -> Sinv (SPD, no pivoting, divergence-free) ----
    float Ii[8][2];
    #pragma unroll
    for (int i = 0; i < 8; ++i) {
        Ii[i][0] = (2*l   == i) ? 1.f : 0.f;
        Ii[i][1] = (2*l+1 == i) ? 1.f : 0.f;
    }
    float pinvD[8];
    #pragma unroll
    for (int k = 0; k < 8; ++k) {
        const float pv   = bq(S[k][k&1], k>>1);
        const float pinv = __builtin_amdgcn_rcpf(pv);
        pinvD[k] = pinv;                     // final diag of row k is stable after stage k
        #pragma unroll
        for (int i = 0; i < 8; ++i) {
            if (i == k) continue;            // compile-time skip: no lane masking needed
            const float fi = bq(S[i][k&1], k>>1) * pinv;
            S[i][0]  -= fi * S[k][0];   S[i][1]  -= fi * S[k][1];
            Ii[i][0] -= fi * Ii[k][0];  Ii[i][1] -= fi * Ii[k][1];
        }
    }
    #pragma unroll
    for (int i = 0; i < 8; ++i) { Ii[i][0] *= pinvD[i]; Ii[i][1] *= pinvD[i]; }  // Ii = Sinv

    // ---- X = Sinv @ CT  (8x16 col-slab; Sinv[m][j] = bq(Ii[m][j&1], j>>1)) ----
    float X[8][4];
    #pragma unroll
    for (int m = 0; m < 8; ++m) {
        float a0=0.f, a1=0.f, a2=0.f, a3=0.f;
        #pragma unroll
        for (int j = 0; j < 8; ++j) {
            const float s = bq(Ii[m][j&1], j>>1);
            a0 += s*CT[j][0]; a1 += s*CT[j][1]; a2 += s*CT[j][2]; a3 += s*CT[j][3];
        }
        X[m][0]=a0; X[m][1]=a1; X[m][2]=a2; X[m][3]=a3;
    }

    // ---- nm = mean + X^T res  (col-slab; res[m] = bq(resd[m&1], m>>1)) ----
    float nmv[4] = {mn[0], mn[1], mn[2], mn[3]};
    #pragma unroll
    for (int m = 0; m < 8; ++m) {
        const float r = bq(resd[m&1], m>>1);
        nmv[0] += X[m][0]*r; nmv[1] += X[m][1]*r; nmv[2] += X[m][2]*r; nmv[3] += X[m][3]*r;
    }

    // ---- NC = P - CT^T @ X  (in place; CT[m][s] = bq(CT[m][s&3], s>>2)) ----
    #pragma unroll
    for (int s = 0; s < 16; ++s) {
        float a0=P[s][0], a1=P[s][1], a2=P[s][2], a3=P[s][3];
        #pragma unroll
        for (int m = 0; m < 8; ++m) {
            const float c = bq(CT[m][s&3], s>>2);
            a0 -= c*X[m][0]; a1 -= c*X[m][1]; a2 -= c*X[m][2]; a3 -= c*X[m][3];
        }
        P[s][0]=a0; P[s][1]=a1; P[s][2]=a2; P[s][3]=a3;
    }

    // ---- FT loads: FT[t][u] = F[4l+u][t] (per-lane contiguous 256B) ----
    float FT[16][4];
    #pragma unroll
    for (int u = 0; u < 4; ++u)
    #pragma unroll
    for (int p = 0; p < 4; ++p) {
        const float4 t = *reinterpret_cast<const float4*>(Fp + (4*l+u)*16 + 4*p);
        FT[4*p+0][u]=t.x; FT[4*p+1][u]=t.y; FT[4*p+2][u]=t.z; FT[4*p+3][u]=t.w;
    }

    // ---- pred_mean = F @ nm -> coalesced float4 store ----
    {
        float a0=0.f, a1=0.f, a2=0.f, a3=0.f;
        #pragma unroll
        for (int k = 0; k < 16; ++k) {
            const float m = bq(nmv[k&3], k>>2);
            a0 += FT[k][0]*m; a1 += FT[k][1]*m; a2 += FT[k][2]*m; a3 += FT[k][3]*m;
        }
        *reinterpret_cast<float4*>(g_out + (size_t)g*16 + 4*l) = make_float4(a0,a1,a2,a3);
    }

    // ---- W = F @ NC  (in place into P, one column at a time;
    //      F[i][k] = bq(FT[k][i&3], i>>2)) ----
    #pragma unroll
    for (int u = 0; u < 4; ++u) {
        float W[16];
        #pragma unroll
        for (int i = 0; i < 16; ++i) {
            float a = 0.f;
            #pragma unroll
            for (int k = 0; k < 16; ++k)
                a += bq(FT[k][i&3], i>>2) * P[k][u];
            W[i] = a;
        }
        #pragma unroll
        for (int i = 0; i < 16; ++i) P[i][u] = W[i];
    }

    // ---- pred_cov = W @ F^T + Q, row-streamed with 2-row Q prefetch
    //      (W[i][t] = bq(P[i][t&3], t>>2); coalesced float4 stores) ----
    float* const out_pc = g_out + (size_t)G*16 + (size_t)g*256;
    float4 qa = *reinterpret_cast<const float4*>(Qp + 0*16 + 4*l);
    float4 qb = *reinterpret_cast<const float4*>(Qp + 1*16 + 4*l);
    #pragma unroll
    for (int i = 0; i < 16; ++i) {
        float4 qn = qb;
        if (i < 14) qn = *reinterpret_cast<const float4*>(Qp + (i+2)*16 + 4*l);
        float a0=qa.x, a1=qa.y, a2=qa.z, a3=qa.w;
        #pragma unroll
        for (int t = 0; t < 16; ++t) {
            const float w = bq(P[i][t&3], t>>2);
            a0 += w*FT[t][0]; a1 += w*FT[t][1]; a2 += w*FT[t][2]; a3 += w*FT[t][3];
        }
        *reinterpret_cast<float4*>(out_pc + i*16 + 4*l) = make_float4(a0,a1,a2,a3);
        qa = qb; qb = qn;
    }
}

extern "C" void kernel_launch(void* const* d_in, const int* in_sizes, int n_in,
                              void* d_out, int out_size, void* d_ws, size_t ws_size,
                              hipStream_t stream) {
    const float* g_in   = (const float*)d_in[0];
    const float* g_mean = (const float*)d_in[1];
    const float* g_cov  = (const float*)d_in[2];
    const float* g_H    = (const float*)d_in[3];
    const float* g_R    = (const float*)d_in[4];
    const float* g_F    = (const float*)d_in[5];
    const float* g_Q    = (const float*)d_in[6];
    float* out = (float*)d_out;
    const int G = in_sizes[2] / 256;     // cov is [G,16,16]
    kalman_kernel<<<G/64, 256, 0, stream>>>(g_in, g_mean, g_cov, g_H, g_R, g_F, g_Q, out, G);
}